// Round 16
// baseline (264.763 us; speedup 1.0000x reference)
//
#include <hip/hip_runtime.h>
#include <hip/hip_bf16.h>

#define N_NODES 10000
#define N_EDGES 320000
#define CDIM    256
#define B_PRE   80
#define EPB     (N_EDGES / B_PRE)   // 4000
#define SLK     130                 // GEMM LDS row stride (halves): 65 dw, odd -> 16-bank spread
#define SA      86                  // alpha LDS row stride (dwords)

typedef __attribute__((ext_vector_type(8))) _Float16 half8;
typedef __attribute__((ext_vector_type(4))) _Float16 half4;
typedef __attribute__((ext_vector_type(4))) float floatx4;

// ---- ws offsets (bytes), total ~11.83 MB ----
#define OFF_RS    0           // rs: 10001 int
#define OFF_INVC  40960       // invc: 10000 f32
#define OFF_S2    81920       // s2: 20000 f32
#define OFF_COLV  163840      // colv: 320000 u16
#define OFF_WCAT  806912      // wcatT: 3*512*256 f16
#define OFF_HN    1593344     // hn: 10000*256 f16
#define OFF_HX    6713344     // hx: 10000*256 f16
// preproc scratch aliased into hn/hx (dead until first k_gemm):
#define OFF_PERC  OFF_HN                  // 80*10000 u16 = 1.6 MB
#define OFF_BASE  (OFF_HN + 1600000)      // 80*10000 int = 3.2 MB
#define OFF_EA2   OFF_HX                  // 320000 float2 = 2.56 MB
#define OFF_CTOT  (OFF_HX + 2560000)      // 10000 int = 40 KB
#define OFF_DONE  (OFF_HX + 2600000)      // 1 int

// ---------------- phase1: x->f16 (0..2499) + weight pack (2500..2883) + count (2884..2963) ----------------
__global__ __launch_bounds__(256) void k_phase1(const float4* __restrict__ x, half4* __restrict__ hB,
                                                const float* __restrict__ neigh_w, const float* __restrict__ node_w,
                                                _Float16* __restrict__ wcatT,
                                                const int* __restrict__ ei, unsigned short* __restrict__ percnt,
                                                int* __restrict__ done) {
  const int b = blockIdx.x;
  if (b < 2500) {
    int i = b * 256 + threadIdx.x;   // 640000 exactly
    float4 v = x[i];
    half4 h; h.x = (_Float16)v.x; h.y = (_Float16)v.y; h.z = (_Float16)v.z; h.w = (_Float16)v.w;
    hB[i] = h;
    return;
  }
  if (b < 2884) {
    __shared__ float t[32][33];
    const int bb = b - 2500;                 // 384 = 8 k-tiles x 16 n-tiles x 3 layers
    const int k0 = (bb & 7) * 32;
    const int n0 = ((bb >> 3) & 15) * 32;
    const int l  = bb >> 7;
    const int tx = threadIdx.x & 31;
    const int ty = threadIdx.x >> 5;   // 0..7
    const float* src = (n0 < 256) ? neigh_w : node_w;
    const int nb = (n0 < 256) ? n0 : (n0 - 256);
#pragma unroll
    for (int p = 0; p < 4; ++p) {
      int k = k0 + ty + p * 8;
      t[ty + p * 8][tx] = src[l * 65536 + k * 256 + (nb + tx)];   // coalesced in n
    }
    __syncthreads();
#pragma unroll
    for (int p = 0; p < 4; ++p) {
      int n = n0 + ty + p * 8;
      wcatT[(size_t)l * 131072 + n * 256 + (k0 + tx)] = (_Float16)t[tx][ty + p * 8];  // coalesced in k
    }
    return;
  }
  // count part: per-block LDS histogram
  __shared__ int hist[N_NODES];
  const int cb = b - 2884;             // 0..79
  const int t = threadIdx.x;
  if (b == 2884 && t == 0) *done = 0;  // reset arrival counter for k_basescan
  for (int n = t; n < N_NODES; n += 256) hist[n] = 0;
  __syncthreads();
  const int e0 = cb * EPB;
  for (int e = e0 + t; e < e0 + EPB; e += 256)
    atomicAdd(&hist[ei[N_EDGES + e]], 1);        // LDS atomic (CU-local)
  __syncthreads();
  for (int n = t; n < N_NODES; n += 256)
    percnt[cb * N_NODES + n] = (unsigned short)hist[n];
}

// ---------------- base (10 blocks x 1024) + last-block scan ----------------
__global__ __launch_bounds__(1024) void k_basescan(const unsigned short* __restrict__ percnt,
                                                   int* __restrict__ prefix, int* __restrict__ cnttot,
                                                   int* __restrict__ done,
                                                   int* __restrict__ rs, float* __restrict__ invc) {
  __shared__ int lds[1024];
  __shared__ int amLast;
  const int t = threadIdx.x;
  const int n = blockIdx.x * 1024 + t;
  if (n < N_NODES) {
    int s = 0;
    for (int b = 0; b < B_PRE; ++b) {
      prefix[b * N_NODES + n] = s;
      s += (int)percnt[b * N_NODES + n];
    }
    cnttot[n] = s;
  }
  __threadfence();                       // publish cnttot (device scope)
  __syncthreads();
  if (t == 0) amLast = (atomicAdd(done, 1) == gridDim.x - 1) ? 1 : 0;
  __syncthreads();
  if (!amLast) return;
  __threadfence();                       // acquire: see all blocks' cnttot

  // scan phase (single block of 1024)
  const int base = t * 10;
  int loc[10];
  int sum = 0;
#pragma unroll
  for (int i = 0; i < 10; ++i) {
    int idx = base + i;
    int v = (idx < N_NODES) ? cnttot[idx] : 0;
    loc[i] = v; sum += v;
  }
  lds[t] = sum; __syncthreads();
  for (int off = 1; off < 1024; off <<= 1) {
    int v = 0;
    if (t >= off) v = lds[t - off];
    __syncthreads();
    if (t >= off) lds[t] += v;
    __syncthreads();
  }
  int ex = lds[t] - sum;
#pragma unroll
  for (int i = 0; i < 10; ++i) {
    int idx = base + i;
    if (idx < N_NODES) {
      rs[idx] = ex; ex += loc[i];
      invc[idx] = (loc[i] > 0) ? (1.0f / (float)loc[i]) : 0.0f;
    }
  }
  if (t == 1023) rs[N_NODES] = lds[1023];
}

__global__ __launch_bounds__(1024) void k_scat(const int* __restrict__ ei, const float* __restrict__ ea,
                                               const int* __restrict__ prefix, const int* __restrict__ rs,
                                               unsigned short* __restrict__ colv, float2* __restrict__ ea2) {
  __shared__ int cur[N_NODES];
  const int t = threadIdx.x, b = blockIdx.x;
  for (int n = t; n < N_NODES; n += 1024)
    cur[n] = rs[n] + prefix[b * N_NODES + n];
  __syncthreads();
  const int e0 = b * EPB;
  for (int e = e0 + t; e < e0 + EPB; e += 1024) {
    int d = ei[N_EDGES + e];
    int src = ei[e];
    float2 a = ((const float2*)ea)[e];
    int pos = atomicAdd(&cur[d], 1);             // LDS atomic
    colv[pos] = (unsigned short)src;
    ea2[pos] = a;
  }
}

__global__ __launch_bounds__(256) void k_s2(const int* __restrict__ rs, const float2* __restrict__ ea2,
                                            float* __restrict__ s2) {
  int n = blockIdx.x * 256 + threadIdx.x;
  if (n >= N_NODES) return;
  int beg = rs[n], end = rs[n + 1];
  float sx = 0.f, sy = 0.f;
  for (int p = beg; p < end; ++p) { float2 a = ea2[p]; sx += a.x; sy += a.y; }
  s2[2 * n] = sx; s2[2 * n + 1] = sy;
}

// ---------------- GEMM: [N x 256] @ [256 x 512] via B^T, fp16 MFMA ----------------
// 64x64 block tile, BK=128 K-loop (K=256 -> 2 iters), LDS 33KB -> 4 blocks/CU.
__global__ __launch_bounds__(256) void k_gemm(const _Float16* __restrict__ A,   // [N][256] f16
                                              const _Float16* __restrict__ BT,  // [512][256] f16
                                              _Float16* __restrict__ hn,        // [N][256] f16
                                              _Float16* __restrict__ hx) {      // [N][256] f16
  __shared__ _Float16 As[64 * SLK];
  __shared__ _Float16 Bs[64 * SLK];
  const int tid = threadIdx.x;
  const int wv = tid >> 6;
  const int lane = tid & 63;
  const int m0 = blockIdx.x * 64;
  const int n0 = blockIdx.y * 64;
  const int wy = wv >> 1, wx = wv & 1;

  floatx4 acc[2][2];
#pragma unroll
  for (int i = 0; i < 2; ++i)
#pragma unroll
    for (int j = 0; j < 2; ++j) acc[i][j] = (floatx4){0.f, 0.f, 0.f, 0.f};

  const int mrow = 32 * wy + (lane & 15);
  const int nrow = 32 * wx + (lane & 15);
  const int q8 = (lane >> 4) * 8;

#pragma unroll
  for (int kt = 0; kt < 2; ++kt) {     // K=256 / BK=128 = 2 iterations
    half8 av[4], bv[4];
#pragma unroll
    for (int c = 0; c < 4; ++c) {
      int ch = tid + 256 * c;            // 0..1023
      int row = ch >> 4;
      int off = (ch & 15) * 8;
      int arow = m0 + row; if (arow >= N_NODES) arow = N_NODES - 1;
      av[c] = *(const half8*)(A + (size_t)arow * 256 + kt * 128 + off);
      bv[c] = *(const half8*)(BT + (size_t)(n0 + row) * 256 + kt * 128 + off);
    }
    __syncthreads();                     // prev iter's LDS reads complete
#pragma unroll
    for (int c = 0; c < 4; ++c) {
      int ch = tid + 256 * c;
      int row = ch >> 4;
      int off = (ch & 15) * 8;
      *(half8*)&As[row * SLK + off] = av[c];
      *(half8*)&Bs[row * SLK + off] = bv[c];
    }
    __syncthreads();
#pragma unroll
    for (int ks = 0; ks < 4; ++ks) {
      const int kb = ks * 32 + q8;
      half8 af0 = *(const half8*)&As[mrow * SLK + kb];
      half8 af1 = *(const half8*)&As[(mrow + 16) * SLK + kb];
      half8 bf0 = *(const half8*)&Bs[nrow * SLK + kb];
      half8 bf1 = *(const half8*)&Bs[(nrow + 16) * SLK + kb];
      acc[0][0] = __builtin_amdgcn_mfma_f32_16x16x32_f16(af0, bf0, acc[0][0], 0, 0, 0);
      acc[0][1] = __builtin_amdgcn_mfma_f32_16x16x32_f16(af0, bf1, acc[0][1], 0, 0, 0);
      acc[1][0] = __builtin_amdgcn_mfma_f32_16x16x32_f16(af1, bf0, acc[1][0], 0, 0, 0);
      acc[1][1] = __builtin_amdgcn_mfma_f32_16x16x32_f16(af1, bf1, acc[1][1], 0, 0, 0);
    }
  }

  // C/D layout: col = lane&15, row = 4*(lane>>4) + r
  const int colb = n0 + 32 * wx + (lane & 15);
  const int rowb = m0 + 32 * wy + 4 * (lane >> 4);
#pragma unroll
  for (int i = 0; i < 2; ++i) {
#pragma unroll
    for (int j = 0; j < 2; ++j) {
      const int cn = colb + 16 * j;
#pragma unroll
      for (int r = 0; r < 4; ++r) {
        const int rw = rowb + 16 * i + r;
        if (rw < N_NODES) {
          float v = acc[i][j][r];
          if (cn < 256) hn[rw * 256 + cn] = (_Float16)v;
          else          hx[rw * 256 + (cn - 256)] = (_Float16)v;
        }
      }
    }
  }
}

// ---------------- aggregate + update + KAF (1024 threads = 16 nodes/block) ----------------
__global__ __launch_bounds__(1024) void k_update(const int* __restrict__ rs, const unsigned short* __restrict__ colv,
                                                 const float* __restrict__ invc, const float* __restrict__ s2,
                                                 const _Float16* __restrict__ hn, const _Float16* __restrict__ hx,
                                                 const float* __restrict__ ew,     // [2][256] f32
                                                 const float* __restrict__ bias,   // [256]    f32
                                                 const float* __restrict__ alpha,  // [256][20] f32
                                                 _Float16* __restrict__ hmid, float* __restrict__ fout,
                                                 int final_layer) {
  __shared__ float alds[64 * SA];      // [q][j][k] layout, staged once per 16 nodes
#pragma unroll
  for (int i = 0; i < 5; ++i) {
    int s = threadIdx.x + 1024 * i;    // 5120 = 1024*5 exact
    int c = s / 20, j = s - 20 * c;
    alds[(c >> 2) * SA + 4 * j + (c & 3)] = alpha[s];
  }
  __syncthreads();

  const int wv   = threadIdx.x >> 6;   // 0..15
  const int lane = threadIdx.x & 63;
  const int hf   = lane >> 5;
  const int l5   = lane & 31;
  const int n = blockIdx.x * 16 + wv;  // 625*16 == N_NODES
  int beg = rs[n], end = rs[n + 1];
  beg = max(0, min(beg, N_EDGES));
  end = max(beg, min(end, N_EDGES));
  const int co = l5 * 8;               // this half-lane's channel offset (x8 f16)

  half8 acc0 = (half8)(_Float16)0.f, acc1 = (half8)(_Float16)0.f;
  half8 acc2 = (half8)(_Float16)0.f, acc3 = (half8)(_Float16)0.f;
  for (int base = beg; base < end; base += 64) {
    const int cnt = min(64, end - base);
    int myIdx = 0;
    if (base + lane < end) myIdx = (int)colv[base + lane];   // coalesced index load
    int j = 0;
    for (; j + 8 <= cnt; j += 8) {                           // 8 edges in flight
      int s0 = __shfl(myIdx, j + hf);
      int s1 = __shfl(myIdx, j + 2 + hf);
      int s2i = __shfl(myIdx, j + 4 + hf);
      int s3 = __shfl(myIdx, j + 6 + hf);
      half8 v0 = *(const half8*)(hn + (size_t)s0 * 256 + co);
      half8 v1 = *(const half8*)(hn + (size_t)s1 * 256 + co);
      half8 v2 = *(const half8*)(hn + (size_t)s2i * 256 + co);
      half8 v3 = *(const half8*)(hn + (size_t)s3 * 256 + co);
      acc0 += v0; acc1 += v1; acc2 += v2; acc3 += v3;
    }
    for (; j + 2 <= cnt; j += 2) {
      int s0 = __shfl(myIdx, j + hf);
      acc0 += *(const half8*)(hn + (size_t)s0 * 256 + co);
    }
    if (j < cnt) {
      int s0 = __shfl(myIdx, j);
      if (hf == 0)
        acc0 += *(const half8*)(hn + (size_t)s0 * 256 + co);
    }
  }
  acc0 = (acc0 + acc2) + (acc1 + acc3);
  // combine the two half-waves (same channels, different edges)
  union { half8 h; unsigned int u[4]; } me, ot;
  me.h = acc0;
#pragma unroll
  for (int r = 0; r < 4; ++r) ot.u[r] = (unsigned int)__shfl_xor((int)me.u[r], 32);
  acc0 = me.h + ot.h;

  const int c0 = l5 * 8 + hf * 4;
  float a0, a1, a2, a3;
  if (hf) { a0 = (float)acc0[4]; a1 = (float)acc0[5]; a2 = (float)acc0[6]; a3 = (float)acc0[7]; }
  else    { a0 = (float)acc0[0]; a1 = (float)acc0[1]; a2 = (float)acc0[2]; a3 = (float)acc0[3]; }

  const int q = c0 >> 2;
  const float ic = invc[n];
  const float t0 = s2[2 * n], t1 = s2[2 * n + 1];
  const half4  hv = ((const half4*)hx)[n * 64 + q];
  const float4 e0 = ((const float4*)ew)[q];
  const float4 e1 = ((const float4*)ew)[64 + q];
  const float4 bi = ((const float4*)bias)[q];
  float s[4];
  s[0] = (a0 + t0 * e0.x + t1 * e1.x) * ic + (float)hv.x + bi.x;
  s[1] = (a1 + t0 * e0.y + t1 * e1.y) * ic + (float)hv.y + bi.y;
  s[2] = (a2 + t0 * e0.z + t1 * e1.z) * ic + (float)hv.z + bi.z;
  s[3] = (a3 + t0 * e0.w + t1 * e1.w) * ic + (float)hv.w + bi.w;

  const float G = -0.705078125f;               // -0.5/(2*interval)^2, interval = 8/19
  const float dp = 8.0f / 19.0f;
  const float* ar = &alds[q * SA];
  float o0 = 0.f, o1 = 0.f, o2 = 0.f, o3 = 0.f;
#pragma unroll
  for (int j = 0; j < 20; ++j) {
    float2 a01 = *(const float2*)(ar + 4 * j);
    float2 a23 = *(const float2*)(ar + 4 * j + 2);
    const float p = -4.0f + dp * (float)j;
    float x0 = s[0] - p, x1 = s[1] - p, x2 = s[2] - p, x3 = s[3] - p;
    o0 += a01.x * __expf(G * x0 * x0);
    o1 += a01.y * __expf(G * x1 * x1);
    o2 += a23.x * __expf(G * x2 * x2);
    o3 += a23.y * __expf(G * x3 * x3);
  }
  if (final_layer) {
    float4 w; w.x = o0; w.y = o1; w.z = o2; w.w = o3;
    ((float4*)fout)[n * 64 + q] = w;
  } else {
    half4 w; w.x = (_Float16)o0; w.y = (_Float16)o1; w.z = (_Float16)o2; w.w = (_Float16)o3;
    ((half4*)hmid)[n * 64 + q] = w;
  }
}

// ---------------- launch ----------------
extern "C" void kernel_launch(void* const* d_in, const int* in_sizes, int n_in,
                              void* d_out, int out_size, void* d_ws, size_t ws_size,
                              hipStream_t stream) {
  const float* x       = (const float*)d_in[0];
  const int*   ei      = (const int*)d_in[1];
  const float* ea      = (const float*)d_in[2];
  const float* node_w  = (const float*)d_in[3];
  const float* edge_w  = (const float*)d_in[4];
  const float* neigh_w = (const float*)d_in[5];
  const float* bias    = (const float*)d_in[6];
  const float* alpha   = (const float*)d_in[7];

  char* w = (char*)d_ws;
  int*            rs     = (int*)(w + OFF_RS);
  float*          invc   = (float*)(w + OFF_INVC);
  float*          s2     = (float*)(w + OFF_S2);
  unsigned short* colv   = (unsigned short*)(w + OFF_COLV);
  _Float16*       wcatT  = (_Float16*)(w + OFF_WCAT);
  _Float16*       hn     = (_Float16*)(w + OFF_HN);
  _Float16*       hx     = (_Float16*)(w + OFF_HX);
  unsigned short* percnt = (unsigned short*)(w + OFF_PERC);
  int*            prefix = (int*)(w + OFF_BASE);
  float2*         ea2    = (float2*)(w + OFF_EA2);
  int*            cnttot = (int*)(w + OFF_CTOT);
  int*            done   = (int*)(w + OFF_DONE);
  float*          fout   = (float*)d_out;
  _Float16*       hB     = (_Float16*)d_out;   // f16 h ping (consumed by k_gemm before rewrite)

  k_phase1<<<2964, 256, 0, stream>>>((const float4*)x, (half4*)hB, neigh_w, node_w, wcatT,
                                     ei, percnt, done);
  k_basescan<<<10, 1024, 0, stream>>>(percnt, prefix, cnttot, done, rs, invc);
  k_scat<<<B_PRE, 1024, 0, stream>>>(ei, ea, prefix, rs, colv, ea2);
  k_s2<<<40, 256, 0, stream>>>(rs, ea2, s2);

  for (int l = 0; l < 3; ++l) {
    k_gemm<<<dim3(157, 8, 1), 256, 0, stream>>>(hB, wcatT + l * 131072, hn, hx);
    k_update<<<625, 1024, 0, stream>>>(rs, colv, invc, s2, hn, hx,
                                       edge_w + l * 512, bias + l * 256, alpha + l * 5120,
                                       hB, fout, (l == 2) ? 1 : 0);
  }
}

// Round 17
// 244.687 us; speedup vs baseline: 1.0820x; 1.0820x over previous
//
#include <hip/hip_runtime.h>
#include <hip/hip_bf16.h>

#define N_NODES 10000
#define N_EDGES 320000
#define CDIM    256
#define B_PRE   80
#define EPB     (N_EDGES / B_PRE)   // 4000
#define SLK     130                 // GEMM LDS row stride (halves): 65 dw, odd -> 16-bank spread
#define SA      86                  // alpha LDS row stride (dwords)

typedef __attribute__((ext_vector_type(8))) _Float16 half8;
typedef __attribute__((ext_vector_type(4))) _Float16 half4;
typedef __attribute__((ext_vector_type(4))) float floatx4;

// ---- ws offsets (bytes), total ~11.83 MB ----
#define OFF_RS    0           // rs: 10001 int
#define OFF_INVC  40960       // invc: 10000 f32
#define OFF_S2    81920       // s2: 20000 f32
#define OFF_COLV  163840      // colv: 320000 u16
#define OFF_WCAT  806912      // wcatT: 3*512*256 f16
#define OFF_HN    1593344     // hn: 10000*256 f16
#define OFF_HX    6713344     // hx: 10000*256 f16
// preproc scratch aliased into hn/hx (dead until first k_gemm):
#define OFF_PERC  OFF_HN                  // 80*10000 u16 = 1.6 MB
#define OFF_BASE  (OFF_HN + 1600000)      // 80*10000 int = 3.2 MB
#define OFF_EA2   OFF_HX                  // 320000 float2 = 2.56 MB
#define OFF_CTOT  (OFF_HX + 2560000)      // 10000 int = 40 KB
#define OFF_DONE  (OFF_HX + 2600000)      // 1 int

// ---------------- fused: x->f16 convert (blocks 0..2499) + weight pack (2500..2883) ----------------
__global__ __launch_bounds__(256) void k_prep(const float4* __restrict__ x, half4* __restrict__ hB,
                                              const float* __restrict__ neigh_w, const float* __restrict__ node_w,
                                              _Float16* __restrict__ wcatT) {
  __shared__ float t[32][33];
  const int b = blockIdx.x;
  if (b < 2500) {
    int i = b * 256 + threadIdx.x;   // 640000 exactly
    float4 v = x[i];
    half4 h; h.x = (_Float16)v.x; h.y = (_Float16)v.y; h.z = (_Float16)v.z; h.w = (_Float16)v.w;
    hB[i] = h;
    return;
  }
  const int bb = b - 2500;                 // 384 = 8 k-tiles x 16 n-tiles x 3 layers
  const int k0 = (bb & 7) * 32;
  const int n0 = ((bb >> 3) & 15) * 32;
  const int l  = bb >> 7;
  const int tx = threadIdx.x & 31;
  const int ty = threadIdx.x >> 5;   // 0..7
  const float* src = (n0 < 256) ? neigh_w : node_w;
  const int nb = (n0 < 256) ? n0 : (n0 - 256);
#pragma unroll
  for (int p = 0; p < 4; ++p) {
    int k = k0 + ty + p * 8;
    t[ty + p * 8][tx] = src[l * 65536 + k * 256 + (nb + tx)];   // coalesced in n
  }
  __syncthreads();
#pragma unroll
  for (int p = 0; p < 4; ++p) {
    int n = n0 + ty + p * 8;
    wcatT[(size_t)l * 131072 + n * 256 + (k0 + tx)] = (_Float16)t[tx][ty + p * 8];  // coalesced in k
  }
}

// ---------------- CSR build: LDS atomics, 80-block parallelism ----------------
__global__ __launch_bounds__(1024) void k_count(const int* __restrict__ ei,
                                                unsigned short* __restrict__ percnt,
                                                int* __restrict__ done) {
  __shared__ int hist[N_NODES];
  const int t = threadIdx.x, b = blockIdx.x;
  if (b == 0 && t == 0) *done = 0;       // reset arrival counter for k_basescan
  for (int n = t; n < N_NODES; n += 1024) hist[n] = 0;
  __syncthreads();
  const int e0 = b * EPB;
  for (int e = e0 + t; e < e0 + EPB; e += 1024)
    atomicAdd(&hist[ei[N_EDGES + e]], 1);        // LDS atomic (CU-local)
  __syncthreads();
  for (int n = t; n < N_NODES; n += 1024)
    percnt[b * N_NODES + n] = (unsigned short)hist[n];
}

// ---------------- base (10 blocks x 1024) + last-block scan ----------------
__global__ __launch_bounds__(1024) void k_basescan(const unsigned short* __restrict__ percnt,
                                                   int* __restrict__ prefix, int* __restrict__ cnttot,
                                                   int* __restrict__ done,
                                                   int* __restrict__ rs, float* __restrict__ invc) {
  __shared__ int lds[1024];
  __shared__ int amLast;
  const int t = threadIdx.x;
  const int n = blockIdx.x * 1024 + t;
  if (n < N_NODES) {
    int s = 0;
    for (int b = 0; b < B_PRE; ++b) {
      prefix[b * N_NODES + n] = s;
      s += (int)percnt[b * N_NODES + n];
    }
    cnttot[n] = s;
  }
  __threadfence();                       // publish cnttot (device scope)
  __syncthreads();
  if (t == 0) amLast = (atomicAdd(done, 1) == gridDim.x - 1) ? 1 : 0;
  __syncthreads();
  if (!amLast) return;
  __threadfence();                       // acquire: see all blocks' cnttot

  // scan phase (single block of 1024)
  const int base = t * 10;
  int loc[10];
  int sum = 0;
#pragma unroll
  for (int i = 0; i < 10; ++i) {
    int idx = base + i;
    int v = (idx < N_NODES) ? cnttot[idx] : 0;
    loc[i] = v; sum += v;
  }
  lds[t] = sum; __syncthreads();
  for (int off = 1; off < 1024; off <<= 1) {
    int v = 0;
    if (t >= off) v = lds[t - off];
    __syncthreads();
    if (t >= off) lds[t] += v;
    __syncthreads();
  }
  int ex = lds[t] - sum;
#pragma unroll
  for (int i = 0; i < 10; ++i) {
    int idx = base + i;
    if (idx < N_NODES) {
      rs[idx] = ex; ex += loc[i];
      invc[idx] = (loc[i] > 0) ? (1.0f / (float)loc[i]) : 0.0f;
    }
  }
  if (t == 1023) rs[N_NODES] = lds[1023];
}

__global__ __launch_bounds__(1024) void k_scat(const int* __restrict__ ei, const float* __restrict__ ea,
                                               const int* __restrict__ prefix, const int* __restrict__ rs,
                                               unsigned short* __restrict__ colv, float2* __restrict__ ea2) {
  __shared__ int cur[N_NODES];
  const int t = threadIdx.x, b = blockIdx.x;
  for (int n = t; n < N_NODES; n += 1024)
    cur[n] = rs[n] + prefix[b * N_NODES + n];
  __syncthreads();
  const int e0 = b * EPB;
  for (int e = e0 + t; e < e0 + EPB; e += 1024) {
    int d = ei[N_EDGES + e];
    int src = ei[e];
    float2 a = ((const float2*)ea)[e];
    int pos = atomicAdd(&cur[d], 1);             // LDS atomic
    colv[pos] = (unsigned short)src;
    ea2[pos] = a;
  }
}

__global__ __launch_bounds__(256) void k_s2(const int* __restrict__ rs, const float2* __restrict__ ea2,
                                            float* __restrict__ s2) {
  int n = blockIdx.x * 256 + threadIdx.x;
  if (n >= N_NODES) return;
  int beg = rs[n], end = rs[n + 1];
  float sx = 0.f, sy = 0.f;
  for (int p = beg; p < end; ++p) { float2 a = ea2[p]; sx += a.x; sy += a.y; }
  s2[2 * n] = sx; s2[2 * n + 1] = sy;
}

// ---------------- GEMM: [N x 256] @ [256 x 512] via B^T, fp16 MFMA ----------------
// 64x64 block tile, BK=128 K-loop (K=256 -> 2 iters), LDS 33KB -> 4 blocks/CU.
__global__ __launch_bounds__(256) void k_gemm(const _Float16* __restrict__ A,   // [N][256] f16
                                              const _Float16* __restrict__ BT,  // [512][256] f16
                                              _Float16* __restrict__ hn,        // [N][256] f16
                                              _Float16* __restrict__ hx) {      // [N][256] f16
  __shared__ _Float16 As[64 * SLK];
  __shared__ _Float16 Bs[64 * SLK];
  const int tid = threadIdx.x;
  const int wv = tid >> 6;
  const int lane = tid & 63;
  const int m0 = blockIdx.x * 64;
  const int n0 = blockIdx.y * 64;
  const int wy = wv >> 1, wx = wv & 1;

  floatx4 acc[2][2];
#pragma unroll
  for (int i = 0; i < 2; ++i)
#pragma unroll
    for (int j = 0; j < 2; ++j) acc[i][j] = (floatx4){0.f, 0.f, 0.f, 0.f};

  const int mrow = 32 * wy + (lane & 15);
  const int nrow = 32 * wx + (lane & 15);
  const int q8 = (lane >> 4) * 8;

#pragma unroll
  for (int kt = 0; kt < 2; ++kt) {     // K=256 / BK=128 = 2 iterations
    half8 av[4], bv[4];
#pragma unroll
    for (int c = 0; c < 4; ++c) {
      int ch = tid + 256 * c;            // 0..1023
      int row = ch >> 4;
      int off = (ch & 15) * 8;
      int arow = m0 + row; if (arow >= N_NODES) arow = N_NODES - 1;
      av[c] = *(const half8*)(A + (size_t)arow * 256 + kt * 128 + off);
      bv[c] = *(const half8*)(BT + (size_t)(n0 + row) * 256 + kt * 128 + off);
    }
    __syncthreads();                     // prev iter's LDS reads complete
#pragma unroll
    for (int c = 0; c < 4; ++c) {
      int ch = tid + 256 * c;
      int row = ch >> 4;
      int off = (ch & 15) * 8;
      *(half8*)&As[row * SLK + off] = av[c];
      *(half8*)&Bs[row * SLK + off] = bv[c];
    }
    __syncthreads();
#pragma unroll
    for (int ks = 0; ks < 4; ++ks) {
      const int kb = ks * 32 + q8;
      half8 af0 = *(const half8*)&As[mrow * SLK + kb];
      half8 af1 = *(const half8*)&As[(mrow + 16) * SLK + kb];
      half8 bf0 = *(const half8*)&Bs[nrow * SLK + kb];
      half8 bf1 = *(const half8*)&Bs[(nrow + 16) * SLK + kb];
      acc[0][0] = __builtin_amdgcn_mfma_f32_16x16x32_f16(af0, bf0, acc[0][0], 0, 0, 0);
      acc[0][1] = __builtin_amdgcn_mfma_f32_16x16x32_f16(af0, bf1, acc[0][1], 0, 0, 0);
      acc[1][0] = __builtin_amdgcn_mfma_f32_16x16x32_f16(af1, bf0, acc[1][0], 0, 0, 0);
      acc[1][1] = __builtin_amdgcn_mfma_f32_16x16x32_f16(af1, bf1, acc[1][1], 0, 0, 0);
    }
  }

  // C/D layout: col = lane&15, row = 4*(lane>>4) + r
  const int colb = n0 + 32 * wx + (lane & 15);
  const int rowb = m0 + 32 * wy + 4 * (lane >> 4);
#pragma unroll
  for (int i = 0; i < 2; ++i) {
#pragma unroll
    for (int j = 0; j < 2; ++j) {
      const int cn = colb + 16 * j;
#pragma unroll
      for (int r = 0; r < 4; ++r) {
        const int rw = rowb + 16 * i + r;
        if (rw < N_NODES) {
          float v = acc[i][j][r];
          if (cn < 256) hn[rw * 256 + cn] = (_Float16)v;
          else          hx[rw * 256 + (cn - 256)] = (_Float16)v;
        }
      }
    }
  }
}

// ---------------- aggregate + update + KAF (round-15 proven version: 256 thr, 2500 blocks) ----------------
__global__ __launch_bounds__(256) void k_update(const int* __restrict__ rs, const unsigned short* __restrict__ colv,
                                                const float* __restrict__ invc, const float* __restrict__ s2,
                                                const _Float16* __restrict__ hn, const _Float16* __restrict__ hx,
                                                const float* __restrict__ ew,     // [2][256] f32
                                                const float* __restrict__ bias,   // [256]    f32
                                                const float* __restrict__ alpha,  // [256][20] f32
                                                _Float16* __restrict__ hmid, float* __restrict__ fout,
                                                int final_layer) {
  __shared__ float alds[64 * SA];      // [q][j][k] layout
#pragma unroll
  for (int i = 0; i < 20; ++i) {
    int s = threadIdx.x + 256 * i;     // 5120 = 256*20 exact
    int c = s / 20, j = s - 20 * c;
    alds[(c >> 2) * SA + 4 * j + (c & 3)] = alpha[s];
  }
  __syncthreads();

  const int wv   = threadIdx.x >> 6;
  const int lane = threadIdx.x & 63;
  const int hf   = lane >> 5;
  const int l5   = lane & 31;
  const int n = blockIdx.x * 4 + wv;   // 2500*4 == N_NODES
  int beg = rs[n], end = rs[n + 1];
  beg = max(0, min(beg, N_EDGES));
  end = max(beg, min(end, N_EDGES));
  const int co = l5 * 8;               // this half-lane's channel offset (x8 f16)

  half8 acc0 = (half8)(_Float16)0.f, acc1 = (half8)(_Float16)0.f;
  half8 acc2 = (half8)(_Float16)0.f, acc3 = (half8)(_Float16)0.f;
  for (int base = beg; base < end; base += 64) {
    const int cnt = min(64, end - base);
    int myIdx = 0;
    if (base + lane < end) myIdx = (int)colv[base + lane];   // coalesced index load
    int j = 0;
    for (; j + 8 <= cnt; j += 8) {                           // 8 edges in flight
      int s0 = __shfl(myIdx, j + hf);
      int s1 = __shfl(myIdx, j + 2 + hf);
      int s2i = __shfl(myIdx, j + 4 + hf);
      int s3 = __shfl(myIdx, j + 6 + hf);
      half8 v0 = *(const half8*)(hn + (size_t)s0 * 256 + co);
      half8 v1 = *(const half8*)(hn + (size_t)s1 * 256 + co);
      half8 v2 = *(const half8*)(hn + (size_t)s2i * 256 + co);
      half8 v3 = *(const half8*)(hn + (size_t)s3 * 256 + co);
      acc0 += v0; acc1 += v1; acc2 += v2; acc3 += v3;
    }
    for (; j + 2 <= cnt; j += 2) {
      int s0 = __shfl(myIdx, j + hf);
      acc0 += *(const half8*)(hn + (size_t)s0 * 256 + co);
    }
    if (j < cnt) {
      int s0 = __shfl(myIdx, j);
      if (hf == 0)
        acc0 += *(const half8*)(hn + (size_t)s0 * 256 + co);
    }
  }
  acc0 = (acc0 + acc2) + (acc1 + acc3);
  // combine the two half-waves (same channels, different edges)
  union { half8 h; unsigned int u[4]; } me, ot;
  me.h = acc0;
#pragma unroll
  for (int r = 0; r < 4; ++r) ot.u[r] = (unsigned int)__shfl_xor((int)me.u[r], 32);
  acc0 = me.h + ot.h;

  const int c0 = l5 * 8 + hf * 4;
  float a0, a1, a2, a3;
  if (hf) { a0 = (float)acc0[4]; a1 = (float)acc0[5]; a2 = (float)acc0[6]; a3 = (float)acc0[7]; }
  else    { a0 = (float)acc0[0]; a1 = (float)acc0[1]; a2 = (float)acc0[2]; a3 = (float)acc0[3]; }

  const int q = c0 >> 2;
  const float ic = invc[n];
  const float t0 = s2[2 * n], t1 = s2[2 * n + 1];
  const half4  hv = ((const half4*)hx)[n * 64 + q];
  const float4 e0 = ((const float4*)ew)[q];
  const float4 e1 = ((const float4*)ew)[64 + q];
  const float4 bi = ((const float4*)bias)[q];
  float s[4];
  s[0] = (a0 + t0 * e0.x + t1 * e1.x) * ic + (float)hv.x + bi.x;
  s[1] = (a1 + t0 * e0.y + t1 * e1.y) * ic + (float)hv.y + bi.y;
  s[2] = (a2 + t0 * e0.z + t1 * e1.z) * ic + (float)hv.z + bi.z;
  s[3] = (a3 + t0 * e0.w + t1 * e1.w) * ic + (float)hv.w + bi.w;

  const float G = -0.705078125f;               // -0.5/(2*interval)^2, interval = 8/19
  const float dp = 8.0f / 19.0f;
  const float* ar = &alds[q * SA];
  float o0 = 0.f, o1 = 0.f, o2 = 0.f, o3 = 0.f;
#pragma unroll
  for (int j = 0; j < 20; ++j) {
    float2 a01 = *(const float2*)(ar + 4 * j);
    float2 a23 = *(const float2*)(ar + 4 * j + 2);
    const float p = -4.0f + dp * (float)j;
    float x0 = s[0] - p, x1 = s[1] - p, x2 = s[2] - p, x3 = s[3] - p;
    o0 += a01.x * __expf(G * x0 * x0);
    o1 += a01.y * __expf(G * x1 * x1);
    o2 += a23.x * __expf(G * x2 * x2);
    o3 += a23.y * __expf(G * x3 * x3);
  }
  if (final_layer) {
    float4 w; w.x = o0; w.y = o1; w.z = o2; w.w = o3;
    ((float4*)fout)[n * 64 + q] = w;
  } else {
    half4 w; w.x = (_Float16)o0; w.y = (_Float16)o1; w.z = (_Float16)o2; w.w = (_Float16)o3;
    ((half4*)hmid)[n * 64 + q] = w;
  }
}

// ---------------- launch ----------------
extern "C" void kernel_launch(void* const* d_in, const int* in_sizes, int n_in,
                              void* d_out, int out_size, void* d_ws, size_t ws_size,
                              hipStream_t stream) {
  const float* x       = (const float*)d_in[0];
  const int*   ei      = (const int*)d_in[1];
  const float* ea      = (const float*)d_in[2];
  const float* node_w  = (const float*)d_in[3];
  const float* edge_w  = (const float*)d_in[4];
  const float* neigh_w = (const float*)d_in[5];
  const float* bias    = (const float*)d_in[6];
  const float* alpha   = (const float*)d_in[7];

  char* w = (char*)d_ws;
  int*            rs     = (int*)(w + OFF_RS);
  float*          invc   = (float*)(w + OFF_INVC);
  float*          s2     = (float*)(w + OFF_S2);
  unsigned short* colv   = (unsigned short*)(w + OFF_COLV);
  _Float16*       wcatT  = (_Float16*)(w + OFF_WCAT);
  _Float16*       hn     = (_Float16*)(w + OFF_HN);
  _Float16*       hx     = (_Float16*)(w + OFF_HX);
  unsigned short* percnt = (unsigned short*)(w + OFF_PERC);
  int*            prefix = (int*)(w + OFF_BASE);
  float2*         ea2    = (float2*)(w + OFF_EA2);
  int*            cnttot = (int*)(w + OFF_CTOT);
  int*            done   = (int*)(w + OFF_DONE);
  float*          fout   = (float*)d_out;
  _Float16*       hB     = (_Float16*)d_out;   // f16 h ping (consumed by k_gemm before rewrite)

  k_prep<<<2884, 256, 0, stream>>>((const float4*)x, (half4*)hB, neigh_w, node_w, wcatT);
  k_count<<<B_PRE, 1024, 0, stream>>>(ei, percnt, done);
  k_basescan<<<10, 1024, 0, stream>>>(percnt, prefix, cnttot, done, rs, invc);
  k_scat<<<B_PRE, 1024, 0, stream>>>(ei, ea, prefix, rs, colv, ea2);
  k_s2<<<40, 256, 0, stream>>>(rs, ea2, s2);

  for (int l = 0; l < 3; ++l) {
    k_gemm<<<dim3(157, 8, 1), 256, 0, stream>>>(hB, wcatT + l * 131072, hn, hx);
    k_update<<<2500, 256, 0, stream>>>(rs, colv, invc, s2, hn, hx,
                                       edge_w + l * 512, bias + l * 256, alpha + l * 5120,
                                       hB, fout, (l == 2) ? 1 : 0);
  }
}

// Round 18
// 231.514 us; speedup vs baseline: 1.1436x; 1.0569x over previous
//
#include <hip/hip_runtime.h>
#include <hip/hip_bf16.h>

#define N_NODES 10000
#define N_EDGES 320000
#define CDIM    256
#define B_PRE   80
#define EPB     (N_EDGES / B_PRE)   // 4000
#define SLK     130                 // GEMM LDS row stride (halves): 65 dw, odd -> 16-bank spread
#define SA      86                  // alpha LDS row stride (dwords)

typedef __attribute__((ext_vector_type(8))) _Float16 half8;
typedef __attribute__((ext_vector_type(4))) _Float16 half4;
typedef __attribute__((ext_vector_type(4))) float floatx4;

// ---- ws offsets (bytes), total ~11.83 MB ----
#define OFF_RS    0           // rs: 10001 int
#define OFF_INVC  40960       // invc: 10000 f32
#define OFF_S2    81920       // s2: 20000 f32
#define OFF_COLV  163840      // colv: 320000 u16
#define OFF_WCAT  806912      // wcatT: 3*512*256 f16
#define OFF_HN    1593344     // hn: 10000*256 f16
#define OFF_HX    6713344     // hx: 10000*256 f16
// preproc scratch aliased into hn/hx (dead until first k_gemm):
#define OFF_PERC  OFF_HN                  // 80*10000 u16 = 1.6 MB
#define OFF_BASE  (OFF_HN + 1600000)      // 80*10000 int = 3.2 MB
#define OFF_EA2   OFF_HX                  // 320000 float2 = 2.56 MB
#define OFF_CTOT  (OFF_HX + 2560000)      // 10000 int = 40 KB

// ---------------- fused: x->f16 convert (blocks 0..2499) + weight pack (2500..2883) ----------------
__global__ __launch_bounds__(256) void k_prep(const float4* __restrict__ x, half4* __restrict__ hB,
                                              const float* __restrict__ neigh_w, const float* __restrict__ node_w,
                                              _Float16* __restrict__ wcatT) {
  __shared__ float t[32][33];
  const int b = blockIdx.x;
  if (b < 2500) {
    int i = b * 256 + threadIdx.x;   // 640000 exactly
    float4 v = x[i];
    half4 h; h.x = (_Float16)v.x; h.y = (_Float16)v.y; h.z = (_Float16)v.z; h.w = (_Float16)v.w;
    hB[i] = h;
    return;
  }
  const int bb = b - 2500;                 // 384 = 8 k-tiles x 16 n-tiles x 3 layers
  const int k0 = (bb & 7) * 32;
  const int n0 = ((bb >> 3) & 15) * 32;
  const int l  = bb >> 7;
  const int tx = threadIdx.x & 31;
  const int ty = threadIdx.x >> 5;   // 0..7
  const float* src = (n0 < 256) ? neigh_w : node_w;
  const int nb = (n0 < 256) ? n0 : (n0 - 256);
#pragma unroll
  for (int p = 0; p < 4; ++p) {
    int k = k0 + ty + p * 8;
    t[ty + p * 8][tx] = src[l * 65536 + k * 256 + (nb + tx)];   // coalesced in n
  }
  __syncthreads();
#pragma unroll
  for (int p = 0; p < 4; ++p) {
    int n = n0 + ty + p * 8;
    wcatT[(size_t)l * 131072 + n * 256 + (k0 + tx)] = (_Float16)t[tx][ty + p * 8];  // coalesced in k
  }
}

// ---------------- CSR build: LDS atomics, 80-block parallelism ----------------
__global__ __launch_bounds__(1024) void k_count(const int* __restrict__ ei,
                                                unsigned short* __restrict__ percnt) {
  __shared__ int hist[N_NODES];
  const int t = threadIdx.x, b = blockIdx.x;
  for (int n = t; n < N_NODES; n += 1024) hist[n] = 0;
  __syncthreads();
  const int e0 = b * EPB;
  for (int e = e0 + t; e < e0 + EPB; e += 1024)
    atomicAdd(&hist[ei[N_EDGES + e]], 1);        // LDS atomic (CU-local)
  __syncthreads();
  for (int n = t; n < N_NODES; n += 1024)
    percnt[b * N_NODES + n] = (unsigned short)hist[n];
}

__global__ __launch_bounds__(256) void k_base(const unsigned short* __restrict__ percnt,
                                              int* __restrict__ prefix, int* __restrict__ cnttot) {
  int n = blockIdx.x * 256 + threadIdx.x;
  if (n >= N_NODES) return;
  int s = 0;
  for (int b = 0; b < B_PRE; ++b) {
    prefix[b * N_NODES + n] = s;
    s += (int)percnt[b * N_NODES + n];
  }
  cnttot[n] = s;
}

__global__ __launch_bounds__(1024) void k_scan(const int* __restrict__ cnttot,
                                               int* __restrict__ rs, float* __restrict__ invc) {
  __shared__ int lds[1024];
  const int t = threadIdx.x;
  const int base = t * 10;
  int loc[10];
  int sum = 0;
#pragma unroll
  for (int i = 0; i < 10; ++i) {
    int idx = base + i;
    int v = (idx < N_NODES) ? cnttot[idx] : 0;
    loc[i] = v; sum += v;
  }
  lds[t] = sum; __syncthreads();
  for (int off = 1; off < 1024; off <<= 1) {
    int v = 0;
    if (t >= off) v = lds[t - off];
    __syncthreads();
    if (t >= off) lds[t] += v;
    __syncthreads();
  }
  int ex = lds[t] - sum;
#pragma unroll
  for (int i = 0; i < 10; ++i) {
    int idx = base + i;
    if (idx < N_NODES) {
      rs[idx] = ex; ex += loc[i];
      invc[idx] = (loc[i] > 0) ? (1.0f / (float)loc[i]) : 0.0f;
    }
  }
  if (t == 1023) rs[N_NODES] = lds[1023];
}

__global__ __launch_bounds__(1024) void k_scat(const int* __restrict__ ei, const float* __restrict__ ea,
                                               const int* __restrict__ prefix, const int* __restrict__ rs,
                                               unsigned short* __restrict__ colv, float2* __restrict__ ea2) {
  __shared__ int cur[N_NODES];
  const int t = threadIdx.x, b = blockIdx.x;
  for (int n = t; n < N_NODES; n += 1024)
    cur[n] = rs[n] + prefix[b * N_NODES + n];
  __syncthreads();
  const int e0 = b * EPB;
  for (int e = e0 + t; e < e0 + EPB; e += 1024) {
    int d = ei[N_EDGES + e];
    int src = ei[e];
    float2 a = ((const float2*)ea)[e];
    int pos = atomicAdd(&cur[d], 1);             // LDS atomic
    colv[pos] = (unsigned short)src;
    ea2[pos] = a;
  }
}

__global__ __launch_bounds__(256) void k_s2(const int* __restrict__ rs, const float2* __restrict__ ea2,
                                            float* __restrict__ s2) {
  int n = blockIdx.x * 256 + threadIdx.x;
  if (n >= N_NODES) return;
  int beg = rs[n], end = rs[n + 1];
  float sx = 0.f, sy = 0.f;
  for (int p = beg; p < end; ++p) { float2 a = ea2[p]; sx += a.x; sy += a.y; }
  s2[2 * n] = sx; s2[2 * n + 1] = sy;
}

// ---------------- GEMM: [N x 256] @ [256 x 512] via B^T, fp16 MFMA ----------------
// 64x64 block tile, BK=128 K-loop (K=256 -> 2 iters), LDS 33KB -> 4 blocks/CU.
__global__ __launch_bounds__(256) void k_gemm(const _Float16* __restrict__ A,   // [N][256] f16
                                              const _Float16* __restrict__ BT,  // [512][256] f16
                                              _Float16* __restrict__ hn,        // [N][256] f16
                                              _Float16* __restrict__ hx) {      // [N][256] f16
  __shared__ _Float16 As[64 * SLK];
  __shared__ _Float16 Bs[64 * SLK];
  const int tid = threadIdx.x;
  const int wv = tid >> 6;
  const int lane = tid & 63;
  const int m0 = blockIdx.x * 64;
  const int n0 = blockIdx.y * 64;
  const int wy = wv >> 1, wx = wv & 1;

  floatx4 acc[2][2];
#pragma unroll
  for (int i = 0; i < 2; ++i)
#pragma unroll
    for (int j = 0; j < 2; ++j) acc[i][j] = (floatx4){0.f, 0.f, 0.f, 0.f};

  const int mrow = 32 * wy + (lane & 15);
  const int nrow = 32 * wx + (lane & 15);
  const int q8 = (lane >> 4) * 8;

#pragma unroll
  for (int kt = 0; kt < 2; ++kt) {     // K=256 / BK=128 = 2 iterations
    half8 av[4], bv[4];
#pragma unroll
    for (int c = 0; c < 4; ++c) {
      int ch = tid + 256 * c;            // 0..1023
      int row = ch >> 4;
      int off = (ch & 15) * 8;
      int arow = m0 + row; if (arow >= N_NODES) arow = N_NODES - 1;
      av[c] = *(const half8*)(A + (size_t)arow * 256 + kt * 128 + off);
      bv[c] = *(const half8*)(BT + (size_t)(n0 + row) * 256 + kt * 128 + off);
    }
    __syncthreads();                     // prev iter's LDS reads complete
#pragma unroll
    for (int c = 0; c < 4; ++c) {
      int ch = tid + 256 * c;
      int row = ch >> 4;
      int off = (ch & 15) * 8;
      *(half8*)&As[row * SLK + off] = av[c];
      *(half8*)&Bs[row * SLK + off] = bv[c];
    }
    __syncthreads();
#pragma unroll
    for (int ks = 0; ks < 4; ++ks) {
      const int kb = ks * 32 + q8;
      half8 af0 = *(const half8*)&As[mrow * SLK + kb];
      half8 af1 = *(const half8*)&As[(mrow + 16) * SLK + kb];
      half8 bf0 = *(const half8*)&Bs[nrow * SLK + kb];
      half8 bf1 = *(const half8*)&Bs[(nrow + 16) * SLK + kb];
      acc[0][0] = __builtin_amdgcn_mfma_f32_16x16x32_f16(af0, bf0, acc[0][0], 0, 0, 0);
      acc[0][1] = __builtin_amdgcn_mfma_f32_16x16x32_f16(af0, bf1, acc[0][1], 0, 0, 0);
      acc[1][0] = __builtin_amdgcn_mfma_f32_16x16x32_f16(af1, bf0, acc[1][0], 0, 0, 0);
      acc[1][1] = __builtin_amdgcn_mfma_f32_16x16x32_f16(af1, bf1, acc[1][1], 0, 0, 0);
    }
  }

  // C/D layout: col = lane&15, row = 4*(lane>>4) + r
  const int colb = n0 + 32 * wx + (lane & 15);
  const int rowb = m0 + 32 * wy + 4 * (lane >> 4);
#pragma unroll
  for (int i = 0; i < 2; ++i) {
#pragma unroll
    for (int j = 0; j < 2; ++j) {
      const int cn = colb + 16 * j;
#pragma unroll
      for (int r = 0; r < 4; ++r) {
        const int rw = rowb + 16 * i + r;
        if (rw < N_NODES) {
          float v = acc[i][j][r];
          if (cn < 256) hn[rw * 256 + cn] = (_Float16)v;
          else          hx[rw * 256 + (cn - 256)] = (_Float16)v;
        }
      }
    }
  }
}

// ---------------- aggregate + update + KAF (alpha staged in LDS) ----------------
__global__ __launch_bounds__(256) void k_update(const int* __restrict__ rs, const unsigned short* __restrict__ colv,
                                                const float* __restrict__ invc, const float* __restrict__ s2,
                                                const _Float16* __restrict__ hn, const _Float16* __restrict__ hx,
                                                const float* __restrict__ ew,     // [2][256] f32
                                                const float* __restrict__ bias,   // [256]    f32
                                                const float* __restrict__ alpha,  // [256][20] f32
                                                _Float16* __restrict__ hmid, float* __restrict__ fout,
                                                int final_layer) {
  __shared__ float alds[64 * SA];      // [q][j][k] layout
#pragma unroll
  for (int i = 0; i < 20; ++i) {
    int s = threadIdx.x + 256 * i;     // 5120 = 256*20 exact
    int c = s / 20, j = s - 20 * c;
    alds[(c >> 2) * SA + 4 * j + (c & 3)] = alpha[s];
  }
  __syncthreads();

  const int wv   = threadIdx.x >> 6;
  const int lane = threadIdx.x & 63;
  const int hf   = lane >> 5;
  const int l5   = lane & 31;
  const int n = blockIdx.x * 4 + wv;   // 2500*4 == N_NODES
  int beg = rs[n], end = rs[n + 1];
  beg = max(0, min(beg, N_EDGES));
  end = max(beg, min(end, N_EDGES));
  const int co = l5 * 8;               // this half-lane's channel offset (x8 f16)

  half8 acc0 = (half8)(_Float16)0.f, acc1 = (half8)(_Float16)0.f;
  half8 acc2 = (half8)(_Float16)0.f, acc3 = (half8)(_Float16)0.f;
  for (int base = beg; base < end; base += 64) {
    const int cnt = min(64, end - base);
    int myIdx = 0;
    if (base + lane < end) myIdx = (int)colv[base + lane];   // coalesced index load
    int j = 0;
    for (; j + 8 <= cnt; j += 8) {                           // 8 edges in flight
      int s0 = __shfl(myIdx, j + hf);
      int s1 = __shfl(myIdx, j + 2 + hf);
      int s2i = __shfl(myIdx, j + 4 + hf);
      int s3 = __shfl(myIdx, j + 6 + hf);
      half8 v0 = *(const half8*)(hn + (size_t)s0 * 256 + co);
      half8 v1 = *(const half8*)(hn + (size_t)s1 * 256 + co);
      half8 v2 = *(const half8*)(hn + (size_t)s2i * 256 + co);
      half8 v3 = *(const half8*)(hn + (size_t)s3 * 256 + co);
      acc0 += v0; acc1 += v1; acc2 += v2; acc3 += v3;
    }
    for (; j + 2 <= cnt; j += 2) {
      int s0 = __shfl(myIdx, j + hf);
      acc0 += *(const half8*)(hn + (size_t)s0 * 256 + co);
    }
    if (j < cnt) {
      int s0 = __shfl(myIdx, j);
      if (hf == 0)
        acc0 += *(const half8*)(hn + (size_t)s0 * 256 + co);
    }
  }
  acc0 = (acc0 + acc2) + (acc1 + acc3);
  // combine the two half-waves (same channels, different edges)
  union { half8 h; unsigned int u[4]; } me, ot;
  me.h = acc0;
#pragma unroll
  for (int r = 0; r < 4; ++r) ot.u[r] = (unsigned int)__shfl_xor((int)me.u[r], 32);
  acc0 = me.h + ot.h;

  const int c0 = l5 * 8 + hf * 4;
  float a0, a1, a2, a3;
  if (hf) { a0 = (float)acc0[4]; a1 = (float)acc0[5]; a2 = (float)acc0[6]; a3 = (float)acc0[7]; }
  else    { a0 = (float)acc0[0]; a1 = (float)acc0[1]; a2 = (float)acc0[2]; a3 = (float)acc0[3]; }

  const int q = c0 >> 2;
  const float ic = invc[n];
  const float t0 = s2[2 * n], t1 = s2[2 * n + 1];
  const half4  hv = ((const half4*)hx)[n * 64 + q];
  const float4 e0 = ((const float4*)ew)[q];
  const float4 e1 = ((const float4*)ew)[64 + q];
  const float4 bi = ((const float4*)bias)[q];
  float s[4];
  s[0] = (a0 + t0 * e0.x + t1 * e1.x) * ic + (float)hv.x + bi.x;
  s[1] = (a1 + t0 * e0.y + t1 * e1.y) * ic + (float)hv.y + bi.y;
  s[2] = (a2 + t0 * e0.z + t1 * e1.z) * ic + (float)hv.z + bi.z;
  s[3] = (a3 + t0 * e0.w + t1 * e1.w) * ic + (float)hv.w + bi.w;

  const float G = -0.705078125f;               // -0.5/(2*interval)^2, interval = 8/19
  const float dp = 8.0f / 19.0f;
  const float* ar = &alds[q * SA];
  float o0 = 0.f, o1 = 0.f, o2 = 0.f, o3 = 0.f;
#pragma unroll
  for (int j = 0; j < 20; ++j) {
    float2 a01 = *(const float2*)(ar + 4 * j);
    float2 a23 = *(const float2*)(ar + 4 * j + 2);
    const float p = -4.0f + dp * (float)j;
    float x0 = s[0] - p, x1 = s[1] - p, x2 = s[2] - p, x3 = s[3] - p;
    o0 += a01.x * __expf(G * x0 * x0);
    o1 += a01.y * __expf(G * x1 * x1);
    o2 += a23.x * __expf(G * x2 * x2);
    o3 += a23.y * __expf(G * x3 * x3);
  }
  if (final_layer) {
    float4 w; w.x = o0; w.y = o1; w.z = o2; w.w = o3;
    ((float4*)fout)[n * 64 + q] = w;
  } else {
    half4 w; w.x = (_Float16)o0; w.y = (_Float16)o1; w.z = (_Float16)o2; w.w = (_Float16)o3;
    ((half4*)hmid)[n * 64 + q] = w;
  }
}

// ---------------- launch ----------------
extern "C" void kernel_launch(void* const* d_in, const int* in_sizes, int n_in,
                              void* d_out, int out_size, void* d_ws, size_t ws_size,
                              hipStream_t stream) {
  const float* x       = (const float*)d_in[0];
  const int*   ei      = (const int*)d_in[1];
  const float* ea      = (const float*)d_in[2];
  const float* node_w  = (const float*)d_in[3];
  const float* edge_w  = (const float*)d_in[4];
  const float* neigh_w = (const float*)d_in[5];
  const float* bias    = (const float*)d_in[6];
  const float* alpha   = (const float*)d_in[7];

  char* w = (char*)d_ws;
  int*            rs     = (int*)(w + OFF_RS);
  float*          invc   = (float*)(w + OFF_INVC);
  float*          s2     = (float*)(w + OFF_S2);
  unsigned short* colv   = (unsigned short*)(w + OFF_COLV);
  _Float16*       wcatT  = (_Float16*)(w + OFF_WCAT);
  _Float16*       hn     = (_Float16*)(w + OFF_HN);
  _Float16*       hx     = (_Float16*)(w + OFF_HX);
  unsigned short* percnt = (unsigned short*)(w + OFF_PERC);
  int*            prefix = (int*)(w + OFF_BASE);
  float2*         ea2    = (float2*)(w + OFF_EA2);
  int*            cnttot = (int*)(w + OFF_CTOT);
  float*          fout   = (float*)d_out;
  _Float16*       hB     = (_Float16*)d_out;   // f16 h ping (consumed by k_gemm before rewrite)

  k_prep<<<2884, 256, 0, stream>>>((const float4*)x, (half4*)hB, neigh_w, node_w, wcatT);
  k_count<<<B_PRE, 1024, 0, stream>>>(ei, percnt);
  k_base<<<40, 256, 0, stream>>>(percnt, prefix, cnttot);
  k_scan<<<1, 1024, 0, stream>>>(cnttot, rs, invc);
  k_scat<<<B_PRE, 1024, 0, stream>>>(ei, ea, prefix, rs, colv, ea2);
  k_s2<<<40, 256, 0, stream>>>(rs, ea2, s2);

  for (int l = 0; l < 3; ++l) {
    k_gemm<<<dim3(157, 8, 1), 256, 0, stream>>>(hB, wcatT + l * 131072, hn, hx);
    k_update<<<2500, 256, 0, stream>>>(rs, colv, invc, s2, hn, hx,
                                       edge_w + l * 512, bias + l * 256, alpha + l * 5120,
                                       hB, fout, (l == 2) ? 1 : 0);
  }
}

// Round 19
// 215.404 us; speedup vs baseline: 1.2291x; 1.0748x over previous
//
#include <hip/hip_runtime.h>
#include <hip/hip_bf16.h>

#define N_NODES 10000
#define N_EDGES 320000
#define CDIM    256
#define B_PRE   80
#define EPB     (N_EDGES / B_PRE)   // 4000
#define SLK     130                 // GEMM LDS row stride (halves): 65 dw, odd -> 16-bank spread
#define SA      84                  // alpha LDS row stride (dwords): 20q mod 32 -> 32 banks, 2-way (free)

typedef __attribute__((ext_vector_type(8))) _Float16 half8;
typedef __attribute__((ext_vector_type(4))) _Float16 half4;
typedef __attribute__((ext_vector_type(4))) float floatx4;

// ---- ws offsets (bytes), total ~11.83 MB ----
#define OFF_RS    0           // rs: 10001 int
#define OFF_INVC  40960       // invc: 10000 f32
#define OFF_S2    81920       // s2: 20000 f32
#define OFF_COLV  163840      // colv: 320000 u16
#define OFF_WCAT  806912      // wcatT: 3*512*256 f16
#define OFF_HN    1593344     // hn: 10000*256 f16
#define OFF_HX    6713344     // hx: 10000*256 f16
// preproc scratch aliased into hn/hx (dead until first k_gemm):
#define OFF_PERC  OFF_HN                  // 80*10000 u16 = 1.6 MB
#define OFF_BASE  (OFF_HN + 1600000)      // 80*10000 int = 3.2 MB
#define OFF_EA2   OFF_HX                  // 320000 float2 = 2.56 MB
#define OFF_CTOT  (OFF_HX + 2560000)      // 10000 int = 40 KB

// ---------------- fused: x->f16 convert (blocks 0..2499) + weight pack (2500..2883) ----------------
__global__ __launch_bounds__(256) void k_prep(const float4* __restrict__ x, half4* __restrict__ hB,
                                              const float* __restrict__ neigh_w, const float* __restrict__ node_w,
                                              _Float16* __restrict__ wcatT) {
  __shared__ float t[32][33];
  const int b = blockIdx.x;
  if (b < 2500) {
    int i = b * 256 + threadIdx.x;   // 640000 exactly
    float4 v = x[i];
    half4 h; h.x = (_Float16)v.x; h.y = (_Float16)v.y; h.z = (_Float16)v.z; h.w = (_Float16)v.w;
    hB[i] = h;
    return;
  }
  const int bb = b - 2500;                 // 384 = 8 k-tiles x 16 n-tiles x 3 layers
  const int k0 = (bb & 7) * 32;
  const int n0 = ((bb >> 3) & 15) * 32;
  const int l  = bb >> 7;
  const int tx = threadIdx.x & 31;
  const int ty = threadIdx.x >> 5;   // 0..7
  const float* src = (n0 < 256) ? neigh_w : node_w;
  const int nb = (n0 < 256) ? n0 : (n0 - 256);
#pragma unroll
  for (int p = 0; p < 4; ++p) {
    int k = k0 + ty + p * 8;
    t[ty + p * 8][tx] = src[l * 65536 + k * 256 + (nb + tx)];   // coalesced in n
  }
  __syncthreads();
#pragma unroll
  for (int p = 0; p < 4; ++p) {
    int n = n0 + ty + p * 8;
    wcatT[(size_t)l * 131072 + n * 256 + (k0 + tx)] = (_Float16)t[tx][ty + p * 8];  // coalesced in k
  }
}

// ---------------- CSR build: LDS atomics, 80-block parallelism ----------------
__global__ __launch_bounds__(1024) void k_count(const int* __restrict__ ei,
                                                unsigned short* __restrict__ percnt) {
  __shared__ int hist[N_NODES];
  const int t = threadIdx.x, b = blockIdx.x;
  for (int n = t; n < N_NODES; n += 1024) hist[n] = 0;
  __syncthreads();
  const int e0 = b * EPB;
  for (int e = e0 + t; e < e0 + EPB; e += 1024)
    atomicAdd(&hist[ei[N_EDGES + e]], 1);        // LDS atomic (CU-local)
  __syncthreads();
  for (int n = t; n < N_NODES; n += 1024)
    percnt[b * N_NODES + n] = (unsigned short)hist[n];
}

__global__ __launch_bounds__(256) void k_base(const unsigned short* __restrict__ percnt,
                                              int* __restrict__ prefix, int* __restrict__ cnttot) {
  int n = blockIdx.x * 256 + threadIdx.x;
  if (n >= N_NODES) return;
  int s = 0;
  for (int b = 0; b < B_PRE; ++b) {
    prefix[b * N_NODES + n] = s;
    s += (int)percnt[b * N_NODES + n];
  }
  cnttot[n] = s;
}

__global__ __launch_bounds__(1024) void k_scan(const int* __restrict__ cnttot,
                                               int* __restrict__ rs, float* __restrict__ invc) {
  __shared__ int lds[1024];
  const int t = threadIdx.x;
  const int base = t * 10;
  int loc[10];
  int sum = 0;
#pragma unroll
  for (int i = 0; i < 10; ++i) {
    int idx = base + i;
    int v = (idx < N_NODES) ? cnttot[idx] : 0;
    loc[i] = v; sum += v;
  }
  lds[t] = sum; __syncthreads();
  for (int off = 1; off < 1024; off <<= 1) {
    int v = 0;
    if (t >= off) v = lds[t - off];
    __syncthreads();
    if (t >= off) lds[t] += v;
    __syncthreads();
  }
  int ex = lds[t] - sum;
#pragma unroll
  for (int i = 0; i < 10; ++i) {
    int idx = base + i;
    if (idx < N_NODES) {
      rs[idx] = ex; ex += loc[i];
      invc[idx] = (loc[i] > 0) ? (1.0f / (float)loc[i]) : 0.0f;
    }
  }
  if (t == 1023) rs[N_NODES] = lds[1023];
}

__global__ __launch_bounds__(1024) void k_scat(const int* __restrict__ ei, const float* __restrict__ ea,
                                               const int* __restrict__ prefix, const int* __restrict__ rs,
                                               unsigned short* __restrict__ colv, float2* __restrict__ ea2) {
  __shared__ int cur[N_NODES];
  const int t = threadIdx.x, b = blockIdx.x;
  for (int n = t; n < N_NODES; n += 1024)
    cur[n] = rs[n] + prefix[b * N_NODES + n];
  __syncthreads();
  const int e0 = b * EPB;
  for (int e = e0 + t; e < e0 + EPB; e += 1024) {
    int d = ei[N_EDGES + e];
    int src = ei[e];
    float2 a = ((const float2*)ea)[e];
    int pos = atomicAdd(&cur[d], 1);             // LDS atomic
    colv[pos] = (unsigned short)src;
    ea2[pos] = a;
  }
}

__global__ __launch_bounds__(256) void k_s2(const int* __restrict__ rs, const float2* __restrict__ ea2,
                                            float* __restrict__ s2) {
  int n = blockIdx.x * 256 + threadIdx.x;
  if (n >= N_NODES) return;
  int beg = rs[n], end = rs[n + 1];
  float sx = 0.f, sy = 0.f;
  for (int p = beg; p < end; ++p) { float2 a = ea2[p]; sx += a.x; sy += a.y; }
  s2[2 * n] = sx; s2[2 * n + 1] = sy;
}

// ---------------- GEMM: [N x 256] @ [256 x 512] via B^T, fp16 MFMA ----------------
// 64x64 block tile, BK=128 K-loop (K=256 -> 2 iters), LDS 33KB -> 4 blocks/CU.
__global__ __launch_bounds__(256) void k_gemm(const _Float16* __restrict__ A,   // [N][256] f16
                                              const _Float16* __restrict__ BT,  // [512][256] f16
                                              _Float16* __restrict__ hn,        // [N][256] f16
                                              _Float16* __restrict__ hx) {      // [N][256] f16
  __shared__ _Float16 As[64 * SLK];
  __shared__ _Float16 Bs[64 * SLK];
  const int tid = threadIdx.x;
  const int wv = tid >> 6;
  const int lane = tid & 63;
  const int m0 = blockIdx.x * 64;
  const int n0 = blockIdx.y * 64;
  const int wy = wv >> 1, wx = wv & 1;

  floatx4 acc[2][2];
#pragma unroll
  for (int i = 0; i < 2; ++i)
#pragma unroll
    for (int j = 0; j < 2; ++j) acc[i][j] = (floatx4){0.f, 0.f, 0.f, 0.f};

  const int mrow = 32 * wy + (lane & 15);
  const int nrow = 32 * wx + (lane & 15);
  const int q8 = (lane >> 4) * 8;

#pragma unroll
  for (int kt = 0; kt < 2; ++kt) {     // K=256 / BK=128 = 2 iterations
    half8 av[4], bv[4];
#pragma unroll
    for (int c = 0; c < 4; ++c) {
      int ch = tid + 256 * c;            // 0..1023
      int row = ch >> 4;
      int off = (ch & 15) * 8;
      int arow = m0 + row; if (arow >= N_NODES) arow = N_NODES - 1;
      av[c] = *(const half8*)(A + (size_t)arow * 256 + kt * 128 + off);
      bv[c] = *(const half8*)(BT + (size_t)(n0 + row) * 256 + kt * 128 + off);
    }
    __syncthreads();                     // prev iter's LDS reads complete
#pragma unroll
    for (int c = 0; c < 4; ++c) {
      int ch = tid + 256 * c;
      int row = ch >> 4;
      int off = (ch & 15) * 8;
      *(half8*)&As[row * SLK + off] = av[c];
      *(half8*)&Bs[row * SLK + off] = bv[c];
    }
    __syncthreads();
#pragma unroll
    for (int ks = 0; ks < 4; ++ks) {
      const int kb = ks * 32 + q8;
      half8 af0 = *(const half8*)&As[mrow * SLK + kb];
      half8 af1 = *(const half8*)&As[(mrow + 16) * SLK + kb];
      half8 bf0 = *(const half8*)&Bs[nrow * SLK + kb];
      half8 bf1 = *(const half8*)&Bs[(nrow + 16) * SLK + kb];
      acc[0][0] = __builtin_amdgcn_mfma_f32_16x16x32_f16(af0, bf0, acc[0][0], 0, 0, 0);
      acc[0][1] = __builtin_amdgcn_mfma_f32_16x16x32_f16(af0, bf1, acc[0][1], 0, 0, 0);
      acc[1][0] = __builtin_amdgcn_mfma_f32_16x16x32_f16(af1, bf0, acc[1][0], 0, 0, 0);
      acc[1][1] = __builtin_amdgcn_mfma_f32_16x16x32_f16(af1, bf1, acc[1][1], 0, 0, 0);
    }
  }

  // C/D layout: col = lane&15, row = 4*(lane>>4) + r
  const int colb = n0 + 32 * wx + (lane & 15);
  const int rowb = m0 + 32 * wy + 4 * (lane >> 4);
#pragma unroll
  for (int i = 0; i < 2; ++i) {
#pragma unroll
    for (int j = 0; j < 2; ++j) {
      const int cn = colb + 16 * j;
#pragma unroll
      for (int r = 0; r < 4; ++r) {
        const int rw = rowb + 16 * i + r;
        if (rw < N_NODES) {
          float v = acc[i][j][r];
          if (cn < 256) hn[rw * 256 + cn] = (_Float16)v;
          else          hx[rw * 256 + (cn - 256)] = (_Float16)v;
        }
      }
    }
  }
}

// ---------------- aggregate + update + KAF (geometric-recurrence KAF) ----------------
__global__ __launch_bounds__(256) void k_update(const int* __restrict__ rs, const unsigned short* __restrict__ colv,
                                                const float* __restrict__ invc, const float* __restrict__ s2,
                                                const _Float16* __restrict__ hn, const _Float16* __restrict__ hx,
                                                const float* __restrict__ ew,     // [2][256] f32
                                                const float* __restrict__ bias,   // [256]    f32
                                                const float* __restrict__ alpha,  // [256][20] f32
                                                _Float16* __restrict__ hmid, float* __restrict__ fout,
                                                int final_layer) {
  __shared__ float alds[64 * SA];      // [q][j][k] layout, float4 rows per j
#pragma unroll
  for (int i = 0; i < 20; ++i) {
    int s = threadIdx.x + 256 * i;     // 5120 = 256*20 exact
    int c = s / 20, j = s - 20 * c;
    alds[(c >> 2) * SA + 4 * j + (c & 3)] = alpha[s];
  }
  __syncthreads();

  const int wv   = threadIdx.x >> 6;
  const int lane = threadIdx.x & 63;
  const int hf   = lane >> 5;
  const int l5   = lane & 31;
  const int n = blockIdx.x * 4 + wv;   // 2500*4 == N_NODES
  int beg = rs[n], end = rs[n + 1];
  beg = max(0, min(beg, N_EDGES));
  end = max(beg, min(end, N_EDGES));
  const int co = l5 * 8;               // this half-lane's channel offset (x8 f16)

  half8 acc0 = (half8)(_Float16)0.f, acc1 = (half8)(_Float16)0.f;
  half8 acc2 = (half8)(_Float16)0.f, acc3 = (half8)(_Float16)0.f;
  for (int base = beg; base < end; base += 64) {
    const int cnt = min(64, end - base);
    int myIdx = 0;
    if (base + lane < end) myIdx = (int)colv[base + lane];   // coalesced index load
    int j = 0;
    for (; j + 8 <= cnt; j += 8) {                           // 8 edges in flight
      int s0 = __shfl(myIdx, j + hf);
      int s1 = __shfl(myIdx, j + 2 + hf);
      int s2i = __shfl(myIdx, j + 4 + hf);
      int s3 = __shfl(myIdx, j + 6 + hf);
      half8 v0 = *(const half8*)(hn + (size_t)s0 * 256 + co);
      half8 v1 = *(const half8*)(hn + (size_t)s1 * 256 + co);
      half8 v2 = *(const half8*)(hn + (size_t)s2i * 256 + co);
      half8 v3 = *(const half8*)(hn + (size_t)s3 * 256 + co);
      acc0 += v0; acc1 += v1; acc2 += v2; acc3 += v3;
    }
    for (; j + 2 <= cnt; j += 2) {
      int s0 = __shfl(myIdx, j + hf);
      acc0 += *(const half8*)(hn + (size_t)s0 * 256 + co);
    }
    if (j < cnt) {
      int s0 = __shfl(myIdx, j);
      if (hf == 0)
        acc0 += *(const half8*)(hn + (size_t)s0 * 256 + co);
    }
  }
  acc0 = (acc0 + acc2) + (acc1 + acc3);
  // combine the two half-waves (same channels, different edges)
  union { half8 h; unsigned int u[4]; } me, ot;
  me.h = acc0;
#pragma unroll
  for (int r = 0; r < 4; ++r) ot.u[r] = (unsigned int)__shfl_xor((int)me.u[r], 32);
  acc0 = me.h + ot.h;

  const int c0 = l5 * 8 + hf * 4;
  float a0, a1, a2, a3;
  if (hf) { a0 = (float)acc0[4]; a1 = (float)acc0[5]; a2 = (float)acc0[6]; a3 = (float)acc0[7]; }
  else    { a0 = (float)acc0[0]; a1 = (float)acc0[1]; a2 = (float)acc0[2]; a3 = (float)acc0[3]; }

  const int q = c0 >> 2;
  const float ic = invc[n];
  const float t0 = s2[2 * n], t1 = s2[2 * n + 1];
  const half4  hv = ((const half4*)hx)[n * 64 + q];
  const float4 e0 = ((const float4*)ew)[q];
  const float4 e1 = ((const float4*)ew)[64 + q];
  const float4 bi = ((const float4*)bias)[q];
  float s[4];
  s[0] = (a0 + t0 * e0.x + t1 * e1.x) * ic + (float)hv.x + bi.x;
  s[1] = (a1 + t0 * e0.y + t1 * e1.y) * ic + (float)hv.y + bi.y;
  s[2] = (a2 + t0 * e0.z + t1 * e1.z) * ic + (float)hv.z + bi.z;
  s[3] = (a3 + t0 * e0.w + t1 * e1.w) * ic + (float)hv.w + bi.w;

  // KAF via exact geometric recurrence (dict pts uniform):
  //   G = -361/512, dp = 8/19  ->  -2*G*dp = 0.59375, G*dp^2 = -0.125 (exact)
  //   K_{j+1} = K_j * r_j ;  r_{j+1} = r_j * exp(2*G*dp^2) = r_j * exp(-0.25)
  const float G  = -0.705078125f;
  const float WM = 0.7788007831f;      // exp(-0.25)
  float K[4], R[4];
#pragma unroll
  for (int k = 0; k < 4; ++k) {
    float t = fminf(fmaxf(s[k], -40.f), 40.f);   // keeps r finite (no 0*inf)
    float d = t + 4.0f;
    K[k] = __expf(G * d * d);
    R[k] = __expf(0.59375f * d - 0.125f);
  }
  const float* ar = &alds[q * SA];
  float o0 = 0.f, o1 = 0.f, o2 = 0.f, o3 = 0.f;
#pragma unroll
  for (int j = 0; j < 20; ++j) {
    float4 a4 = *(const float4*)(ar + 4 * j);
    o0 += a4.x * K[0]; o1 += a4.y * K[1]; o2 += a4.z * K[2]; o3 += a4.w * K[3];
    K[0] *= R[0]; K[1] *= R[1]; K[2] *= R[2]; K[3] *= R[3];
    R[0] *= WM;   R[1] *= WM;   R[2] *= WM;   R[3] *= WM;
  }
  if (final_layer) {
    float4 w; w.x = o0; w.y = o1; w.z = o2; w.w = o3;
    ((float4*)fout)[n * 64 + q] = w;
  } else {
    half4 w; w.x = (_Float16)o0; w.y = (_Float16)o1; w.z = (_Float16)o2; w.w = (_Float16)o3;
    ((half4*)hmid)[n * 64 + q] = w;
  }
}

// ---------------- launch ----------------
extern "C" void kernel_launch(void* const* d_in, const int* in_sizes, int n_in,
                              void* d_out, int out_size, void* d_ws, size_t ws_size,
                              hipStream_t stream) {
  const float* x       = (const float*)d_in[0];
  const int*   ei      = (const int*)d_in[1];
  const float* ea      = (const float*)d_in[2];
  const float* node_w  = (const float*)d_in[3];
  const float* edge_w  = (const float*)d_in[4];
  const float* neigh_w = (const float*)d_in[5];
  const float* bias    = (const float*)d_in[6];
  const float* alpha   = (const float*)d_in[7];

  char* w = (char*)d_ws;
  int*            rs     = (int*)(w + OFF_RS);
  float*          invc   = (float*)(w + OFF_INVC);
  float*          s2     = (float*)(w + OFF_S2);
  unsigned short* colv   = (unsigned short*)(w + OFF_COLV);
  _Float16*       wcatT  = (_Float16*)(w + OFF_WCAT);
  _Float16*       hn     = (_Float16*)(w + OFF_HN);
  _Float16*       hx     = (_Float16*)(w + OFF_HX);
  unsigned short* percnt = (unsigned short*)(w + OFF_PERC);
  int*            prefix = (int*)(w + OFF_BASE);
  float2*         ea2    = (float2*)(w + OFF_EA2);
  int*            cnttot = (int*)(w + OFF_CTOT);
  float*          fout   = (float*)d_out;
  _Float16*       hB     = (_Float16*)d_out;   // f16 h ping (consumed by k_gemm before rewrite)

  k_prep<<<2884, 256, 0, stream>>>((const float4*)x, (half4*)hB, neigh_w, node_w, wcatT);
  k_count<<<B_PRE, 1024, 0, stream>>>(ei, percnt);
  k_base<<<40, 256, 0, stream>>>(percnt, prefix, cnttot);
  k_scan<<<1, 1024, 0, stream>>>(cnttot, rs, invc);
  k_scat<<<B_PRE, 1024, 0, stream>>>(ei, ea, prefix, rs, colv, ea2);
  k_s2<<<40, 256, 0, stream>>>(rs, ea2, s2);

  for (int l = 0; l < 3; ++l) {
    k_gemm<<<dim3(157, 8, 1), 256, 0, stream>>>(hB, wcatT + l * 131072, hn, hx);
    k_update<<<2500, 256, 0, stream>>>(rs, colv, invc, s2, hn, hx,
                                       edge_w + l * 512, bias + l * 256, alpha + l * 5120,
                                       hB, fout, (l == 2) ? 1 : 0);
  }
}